// Round 1
// baseline (199.019 us; speedup 1.0000x reference)
//
#include <hip/hip_runtime.h>

#define NN 256     // Preisach mesh size
#define TT 32      // outputs (steps) per chunk; G = ceil(M/TT) blocks

__device__ __forceinline__ float softplus_f(float x) {
    if (x > 20.0f) return x;
    return log1pf(expf(x));
}

// Single fused kernel, NO workspace. One block per 32-step output chunk.
// Per block:
//   P2: classify every step tau<=t0+Tb; prior steps scatter flip-times into
//       LDS buckets (atomicMax); chunk steps stored as packed records.
//   P3: fused suffix-max(bestU)/prefix-max(bestD) scan -> Ue(row), De(col).
//   P4: carry-in prefix count cc0 = #{j: De[j] < Ue} (De non-decreasing).
//   P5: per-thread serial row-prefix of dens=softplus(raw), sampling the
//       needed positions (block-uniform jh list -> LDS pk_s; per-thread cc0).
//   P6: 32-step walk + 34-quantity wave reduce + 32-wide scan -> out.
__global__ void __launch_bounds__(256)
kFused(const float* __restrict__ h_g, const float* __restrict__ raw,
       float* __restrict__ out, int M)
{
    __shared__ float xs[NN];
    __shared__ int   bestU[NN + 1];       // bestU[ih] = max flip-time of up-steps with that ih
    __shared__ int   bestD[NN + 1];       // bestD[jh] = max flip-time of down-steps with that jh
    __shared__ int   rec_s[TT + 1];       // packed chunk-step records
    __shared__ int   plist[TT];           // sorted (jh<<8 | kk-1) sample positions
    __shared__ float pk_s[TT][NN];        // row-prefix sampled at jh_kk, column tid (bank-conflict-free)
    __shared__ float red[4 * (TT + 2)];
    __shared__ float tot[TT + 2];

    const int tid  = threadIdx.x;
    const int c    = blockIdx.x;
    const int t0   = c * TT;
    const int Tb   = min(TT, M - t0);
    const int tmax = t0 + Tb;

    xs[tid] = (float)((double)tid / 255.0);   // np.linspace(0,1,256) f64->f32 (matches verified kernel)
    bestU[tid] = 0; bestD[tid] = 0;
    if (tid == 0) { bestU[NN] = 0; bestD[NN] = 0; }
    if (tid < TT) rec_s[1 + tid] = 0;
    #pragma unroll
    for (int kk = 0; kk < TT; ++kk) pk_s[kk][tid] = 0.0f;   // stride-256 -> lane==bank, conflict-free
    __syncthreads();

    // ---- P2: step classification. tau = 1..tmax, thread-strided ----
    for (int tau = 1 + tid; tau <= tmax; tau += NN) {
        float cur  = (h_g[tau - 1] + 1.0f) * 0.5f;
        float prev = (tau == 1) ? 1.0f : (h_g[tau - 2] + 1.0f) * 0.5f;
        int d = (cur > prev) ? 2 : ((cur < prev) ? 0 : 1);
        // ih = #{x < cur}, jh = #{x <= cur}; arithmetic seed + monotone advance
        // (g <= true boundary by construction: xs[g] <= (g+eps)/255 < cur)
        int g = (int)(cur * 255.0f) - 2;
        int ih = max(g, 0);
        while (ih < NN && xs[ih] < cur)  ++ih;
        int jh = ih;
        while (jh < NN && xs[jh] <= cur) ++jh;
        if (tau <= t0) {
            if (d == 2)      atomicMax(&bestU[ih], tau + 1);   // up: rows i < ih flipped at tau
            else if (d == 0) atomicMax(&bestD[jh], tau + 1);   // down: cols j >= jh cleared at tau
        } else {
            rec_s[tau - t0] = d | (ih << 2) | (jh << 11);
        }
    }
    __syncthreads();

    // ---- P3: fused suffix-max(bestU) / prefix-max(bestD), in place ----
    for (int off = 1; off <= NN; off <<= 1) {
        int vU = (tid + off <= NN) ? bestU[tid + off] : 0;
        int vD = (tid >= off)      ? bestD[tid - off] : 0;
        __syncthreads();
        if (vU > bestU[tid]) bestU[tid] = vU;
        if (vD > bestD[tid]) bestD[tid] = vD;
        __syncthreads();
    }
    // Ue(row tid) = max over up-steps with ih > tid  (+ virtual tau=0 step, time=1)
    int Ue = bestU[tid + 1];
    float hsM = (h_g[M - 1] + 1.0f) * 0.5f;    // hs[M] (roll wrap), prev of the tau=0 step h=1.0
    if (hsM < 1.0f && tid < NN - 1) Ue = max(Ue, 1);

    // ---- P4: cc0 = #{j : De[j] < Ue}, De = bestD prefix-max (non-decreasing) ----
    {
        int lo = 0, hi = NN;
        while (lo < hi) { int m = (lo + hi) >> 1; if (bestD[m] < Ue) lo = m + 1; else hi = m; }
        Ue = min(lo, tid + 1);                 // reuse Ue as cc0
    }
    const int cc0 = Ue;

    // ---- sorted block-uniform sample positions (32 jh values) ----
    if (tid < TT) {
        int jh_me = (rec_s[1 + tid] >> 11) & 0x1FF;
        int rank = 0;
        for (int j = 0; j < TT; ++j) {
            int oj = (rec_s[1 + j] >> 11) & 0x1FF;
            rank += (oj < jh_me) || (oj == jh_me && j < tid);
        }
        plist[rank] = (jh_me << 8) | tid;      // tid = kk-1
    }
    __syncthreads();

    // ---- P5: serial row-prefix walk with sampling ----
    const float* rowp = raw + (tid * (tid + 1)) / 2;
    float s = 0.0f, pc0 = 0.0f;
    {
        int ptr = 0;
        int nxt = plist[0];
        while ((nxt >> 8) == 0) { ++ptr; nxt = (ptr < TT) ? plist[ptr] : 0x7FFFFFFF; }  // jh=0 -> P(0)=0
        for (int k = 0; k <= tid; ++k) {
            s += softplus_f(rowp[k]);
            if (k + 1 == cc0) pc0 = s;
            while ((nxt >> 8) == k + 1) {
                pk_s[nxt & 255][tid] = s;      // same-thread column; no barrier needed
                ++ptr; nxt = (ptr < TT) ? plist[ptr] : 0x7FFFFFFF;
            }
        }
    }
    const float RT = s;                        // full row total

    // ---- P6: barrier-free 32-step walk (identical to verified kB walk) ----
    float vals[TT + 2];
    vals[0] = RT;
    float ww = 2.0f * pc0 - RT;
    vals[1] = ww;
    int cc = cc0;
    #pragma unroll
    for (int kk = 1; kk <= TT; ++kk) {
        float dl = 0.0f;
        if (kk <= Tb) {
            int rec = rec_s[kk];
            int d = rec & 3;
            if (d == 2) {                      // up: rows i < ih -> full +1
                int ih = (rec >> 2) & 0x1FF;
                if (tid < ih) { dl = RT - ww; ww = RT; cc = tid + 1; }
            } else if (d == 0) {               // down: truncate prefix to jh
                int jh = (rec >> 11) & 0x1FF;
                if (cc > jh) { float wn = 2.0f * pk_s[kk - 1][tid] - RT; dl = wn - ww; ww = wn; cc = jh; }
            }
        }
        vals[1 + kk] = dl;
    }

    // reduce all TT+2 quantities: wave shuffle then cross-wave via LDS
    #pragma unroll
    for (int q = 0; q < TT + 2; ++q)
        for (int off = 32; off; off >>= 1)
            vals[q] += __shfl_down(vals[q], off, 64);
    int lane = tid & 63, wv = tid >> 6;
    if (lane == 0) {
        #pragma unroll
        for (int q = 0; q < TT + 2; ++q) red[wv * (TT + 2) + q] = vals[q];
    }
    __syncthreads();
    if (tid < TT + 2)
        tot[tid] = red[tid] + red[(TT + 2) + tid] + red[2 * (TT + 2) + tid] + red[3 * (TT + 2) + tid];
    __syncthreads();
    if (tid < TT) {                            // 32-lane shuffle prefix-scan of per-step deltas
        float x = tot[2 + tid];
        #pragma unroll
        for (int off = 1; off < TT; off <<= 1) {
            float y = __shfl_up(x, off, 64);
            if (tid >= off) x += y;
        }
        if (tid < Tb) out[t0 + tid] = (tot[1] + x) * (1.0f / tot[0]);
    }
}

extern "C" void kernel_launch(void* const* d_in, const int* in_sizes, int n_in,
                              void* d_out, int out_size, void* d_ws, size_t ws_size,
                              hipStream_t stream) {
    const float* h   = (const float*)d_in[0];
    const float* raw = (const float*)d_in[1];
    float* out = (float*)d_out;
    int M = in_sizes[0];                 // 4000
    int G = (M + TT - 1) / TT;           // 125 chunks
    (void)d_ws; (void)ws_size; (void)n_in; (void)out_size;   // workspace intentionally unused
    kFused<<<G, NN, 0, stream>>>(h, raw, out, M);
}

// Round 3
// 77.203 us; speedup vs baseline: 2.5779x; 2.5779x over previous
//
#include <hip/hip_runtime.h>

#define NN 256     // Preisach mesh size
#define TT 16      // outputs (steps) per chunk; G = ceil(M/TT) = 250 for M=4000

__device__ __forceinline__ float softplus_f(float x) {
    if (x > 20.0f) return x;
    return log1pf(expf(x));
}

// ---- kA: Blocks [0,NN): prefix rows of dens (transposed store).
//          Blocks [NN, NN+G): chunk tables (packed step records + last-flip).
__global__ void __launch_bounds__(256)
kA(const float* __restrict__ h_g, const float* __restrict__ raw, int M, int G,
   float* __restrict__ PrefT, float* __restrict__ RowTot,
   int* __restrict__ steps_g, unsigned int* __restrict__ UDt)
{
    int b = blockIdx.x, tid = threadIdx.x;
    if (b < NN) {
        // per-row prefix sums of dens = softplus(raw) on lower triangle.
        // Intra-wave shuffle scan (segmented), then cross-wave via wave TOTALS
        // (lane 63 of each wave), the correct segmented-scan composition.
        __shared__ float wsum[4];
        float x = 0.0f;
        if (tid <= b) x = softplus_f(raw[b * (b + 1) / 2 + tid]);
        int lane = tid & 63, wv = tid >> 6;
        #pragma unroll
        for (int off = 1; off <= 32; off <<= 1) {
            float y = __shfl_up(x, off, 64);
            if (lane >= off) x += y;
        }
        if (lane == 63) wsum[wv] = x;
        __syncthreads();
        float add = 0.0f;
        if (wv > 0) add += wsum[0];
        if (wv > 1) add += wsum[1];
        if (wv > 2) add += wsum[2];
        x += add;
        PrefT[(tid + 1) * NN + b] = x;             // PrefT[k][i], k=0..256
        if (tid == 0)      PrefT[b] = 0.0f;
        if (tid == NN - 1) RowTot[b] = x;
    } else {
        // chunk c: steps tau in [t0+1, t0+Tb]
        __shared__ float xs[NN];
        __shared__ float hh[TT + 1];
        __shared__ int   dd[TT + 1];
        int c  = b - NN;
        int t0 = c * TT;
        int Tb = min(TT, M - t0);
        xs[tid] = (float)((double)tid / 255.0);    // np.linspace(0,1,256) f64->f32
        __syncthreads();
        if (tid < Tb) {
            int tau = t0 + 1 + tid;
            float cur  = (h_g[tau - 1] + 1.0f) * 0.5f;
            float prev = (tau == 1) ? 1.0f : (h_g[tau - 2] + 1.0f) * 0.5f;
            int d = (cur > prev) ? 2 : ((cur < prev) ? 0 : 1);
            int lo = 0, hi = NN;                   // ih = #{x < cur}
            while (lo < hi) { int m = (lo + hi) >> 1; if (xs[m] < cur) lo = m + 1; else hi = m; }
            int ih = lo;
            lo = 0; hi = NN;                       // jh = #{x <= cur}
            while (lo < hi) { int m = (lo + hi) >> 1; if (xs[m] <= cur) lo = m + 1; else hi = m; }
            int jh = lo;
            hh[1 + tid] = cur;
            dd[1 + tid] = d - 1;
            steps_g[tau] = d | (ih << 2) | (jh << 11);
        }
        __syncthreads();
        float xi = xs[tid];
        int Ue = 0, De = 0;                        // absolute tau+1, 0 = none
        for (int k = 1; k <= Tb; ++k) {
            float hv = hh[k]; int d = dd[k];
            if (d > 0 && hv > xi) Ue = t0 + k + 1;
            if (d < 0 && hv < xi) De = t0 + k + 1;
        }
        UDt[c * NN + tid] = (unsigned)Ue | ((unsigned)De << 16);  // chunk-major
    }
}

// ---- kM: exclusive prefix-max of chunk tables across chunks (one block).
//      PrefUD[c][tid] = carry-in (Ue,De) for chunk c = virtual tau=0 step
//      merged with chunks 0..c-1. Removes kB's O(b) redundant scan.
__global__ void __launch_bounds__(256)
kM(const float* __restrict__ h_g, const unsigned int* __restrict__ UDt,
   unsigned int* __restrict__ PrefUD, int M, int G)
{
    int tid = threadIdx.x;
    float hsM = (h_g[M - 1] + 1.0f) * 0.5f;        // hs[M] (roll wrap)
    unsigned u = (hsM < 1.0f && tid < NN - 1) ? 1u : 0u;
    unsigned d = 0u;
    const unsigned int* p = UDt + tid;
    unsigned int* q = PrefUD + tid;
    int k = 0;
    for (; k + 8 <= G; k += 8) {                   // batch loads for MLP
        unsigned vv[8];
        #pragma unroll
        for (int uu = 0; uu < 8; ++uu) vv[uu] = p[(k + uu) * NN];
        #pragma unroll
        for (int uu = 0; uu < 8; ++uu) {
            q[(k + uu) * NN] = u | (d << 16);
            unsigned ue = vv[uu] & 0xFFFFu, de = vv[uu] >> 16;
            if (ue > u) u = ue;
            if (de > d) d = de;
        }
    }
    for (; k < G; ++k) {
        unsigned v = p[k * NN];
        q[k * NN] = u | (d << 16);
        unsigned ue = v & 0xFFFFu, de = v >> 16;
        if (ue > u) u = ue;
        if (de > d) d = de;
    }
}

// ---- kB: read one carry row + walk 16 steps + reduce ----
__global__ void __launch_bounds__(256)
kB(const int* __restrict__ steps_g, const unsigned int* __restrict__ PrefUD,
   const float* __restrict__ PrefT, const float* __restrict__ RowTot,
   float* __restrict__ out, int M)
{
    __shared__ int   rec_s[TT + 1];
    __shared__ int   Dv[NN];
    __shared__ float red[4 * (TT + 2)];
    __shared__ float tot[TT + 2];
    int b = blockIdx.x, tid = threadIdx.x;
    int t0 = b * TT;
    int Tb = min(TT, M - t0);

    if (tid < TT) rec_s[1 + tid] = (tid < Tb) ? steps_g[t0 + 1 + tid] : 0;
    float RT = RowTot[tid];

    unsigned v = PrefUD[b * NN + tid];             // precomputed carry-in
    int Ue = (int)(v & 0xFFFFu);
    Dv[tid] = (int)(v >> 16);
    __syncthreads();

    // prefetch PrefT rows for each step's jh (coalesced)
    float pk[TT + 1];
    #pragma unroll
    for (int kk = 1; kk <= TT; ++kk) {
        int jh = (rec_s[kk] >> 11) & 0x1FF;
        pk[kk] = PrefT[jh * NN + tid];
    }

    // c = #{j : De_j < Ue} (Dv non-decreasing), clamp to triangle
    int lo = 0, hi = NN;
    while (lo < hi) { int m = (lo + hi) >> 1; if (Dv[m] < Ue) lo = m + 1; else hi = m; }
    int c = min(lo, tid + 1);
    float w = 2.0f * PrefT[c * NN + tid] - RT;

    // barrier-free walk: per-thread deltas per step
    float vals[TT + 2];
    vals[0] = RT; vals[1] = w;
    int cc = c; float ww = w;
    #pragma unroll
    for (int kk = 1; kk <= TT; ++kk) {
        float dl = 0.0f;
        if (kk <= Tb) {
            int rec = rec_s[kk];
            int d = rec & 3;
            if (d == 2) {                          // up: rows i < ih -> +RowTot
                int ih = (rec >> 2) & 0x1FF;
                if (tid < ih) { dl = RT - ww; ww = RT; cc = tid + 1; }
            } else if (d == 0) {                   // down: truncate prefix to jh
                int jh = (rec >> 11) & 0x1FF;
                if (cc > jh) { float wn = 2.0f * pk[kk] - RT; dl = wn - ww; ww = wn; cc = jh; }
            }
        }
        vals[1 + kk] = dl;
    }

    // reduce all TT+2 quantities: wave shuffle then cross-wave via LDS
    #pragma unroll
    for (int q = 0; q < TT + 2; ++q)
        for (int off = 32; off; off >>= 1)
            vals[q] += __shfl_down(vals[q], off, 64);
    int lane = tid & 63, wv = tid >> 6;
    if (lane == 0) {
        #pragma unroll
        for (int q = 0; q < TT + 2; ++q) red[wv * (TT + 2) + q] = vals[q];
    }
    __syncthreads();
    if (tid < TT + 2)
        tot[tid] = red[tid] + red[(TT + 2) + tid] + red[2 * (TT + 2) + tid] + red[3 * (TT + 2) + tid];
    __syncthreads();
    if (tid < TT) {                                // 16-lane shuffle prefix-scan
        float x = tot[2 + tid];
        #pragma unroll
        for (int off = 1; off < TT; off <<= 1) {
            float y = __shfl_up(x, off, 64);
            if (tid >= off) x += y;
        }
        if (tid < Tb) out[t0 + tid] = (tot[1] + x) * (1.0f / tot[0]);
    }
}

extern "C" void kernel_launch(void* const* d_in, const int* in_sizes, int n_in,
                              void* d_out, int out_size, void* d_ws, size_t ws_size,
                              hipStream_t stream) {
    const float* h   = (const float*)d_in[0];
    const float* raw = (const float*)d_in[1];
    float* out = (float*)d_out;
    int M = in_sizes[0];            // 4000
    int G = (M + TT - 1) / TT;      // 250 chunks

    char* ws = (char*)d_ws;
    size_t off = 0;
    auto take = [&](size_t bytes) { size_t cur = off; off = (off + bytes + 255) & ~(size_t)255; return cur; };
    float*        PrefT  = (float*)(ws + take((size_t)(NN + 1) * NN * 4));
    float*        RowTot = (float*)(ws + take((size_t)NN * 4));
    int*          steps  = (int*)(ws + take((size_t)(M + 1) * 4));
    unsigned int* UDt    = (unsigned int*)(ws + take((size_t)G * NN * 4));
    unsigned int* PrefUD = (unsigned int*)(ws + take((size_t)G * NN * 4));

    kA<<<NN + G, 256, 0, stream>>>(h, raw, M, G, PrefT, RowTot, steps, UDt);
    kM<<<1, 256, 0, stream>>>(h, UDt, PrefUD, M, G);
    kB<<<G, 256, 0, stream>>>(steps, PrefUD, PrefT, RowTot, out, M);
}